// Round 6
// baseline (157.238 us; speedup 1.0000x reference)
//
#include <hip/hip_runtime.h>
#include <hip/hip_bf16.h>

// R2 skeleton (proven best: 256 blocks x 256 thr, 1024 rows/block, 2 chains,
// line-aligned 200-thread store loop with cpr/pmx in registers) + scalar-
// weight MLP. Weights are read i-major with uniform indices -> contiguous
// s_load_dwordx8 batches, zero LDS traffic in the MLP. LDS holds only
// cumprev[100] and td[1024]. Head to first store ~1.5us, then the 102.4 MB
// output drains at the fill-measured ~6.5 TB/s (~16.1us).

typedef float f2 __attribute__((ext_vector_type(2)));

#define NBLOCKS 256

// LDS float offsets
#define OFF_CP 0      // cumprev[100] (16B-aligned)
#define OFF_TD 112    // td[1024 rows]
#define SMEM_FLOATS (OFF_TD + 1024)

__device__ __forceinline__ f2 splat2(float v) { return (f2){v, v}; }

// Packed MLP for two rows (xa -> .x lane, xb -> .y lane). i-major layer
// sweeps: all weight reads are wave-uniform contiguous -> scalar loads.
__device__ __forceinline__ f2 mlp_pair(const float4 xa, const float4 xb,
                                       const float* __restrict__ W1,
                                       const float* __restrict__ b1,
                                       const float* __restrict__ W2,
                                       const float* __restrict__ b2,
                                       const float* __restrict__ W3) {
  const f2 zero = {0.0f, 0.0f};
  const f2 X0 = {xa.x, xb.x}, X1 = {xa.y, xb.y};
  const f2 X2 = {xa.z, xb.z}, X3 = {xa.w, xb.w};

  // layer 1: h1[k] = relu(b1[k] + sum_j x_j * W1[j][k]); W1 rows contiguous.
  f2 h1[30];
#pragma unroll
  for (int k = 0; k < 30; ++k) h1[k] = splat2(b1[k]);
#pragma unroll
  for (int k = 0; k < 30; ++k) h1[k] = __builtin_elementwise_fma(X0, splat2(W1[k]),      h1[k]);
#pragma unroll
  for (int k = 0; k < 30; ++k) h1[k] = __builtin_elementwise_fma(X1, splat2(W1[30 + k]), h1[k]);
#pragma unroll
  for (int k = 0; k < 30; ++k) h1[k] = __builtin_elementwise_fma(X2, splat2(W1[60 + k]), h1[k]);
#pragma unroll
  for (int k = 0; k < 30; ++k) h1[k] = __builtin_elementwise_fma(X3, splat2(W1[90 + k]), h1[k]);
#pragma unroll
  for (int k = 0; k < 30; ++k) h1[k] = __builtin_elementwise_max(h1[k], zero);

  // layer 2 i-major: h2[k] += h1[i] * W2[i][k]; W2 row i contiguous -> dwordx8.
  // 30 independent accumulator chains -> full ILP.
  f2 h2[30];
#pragma unroll
  for (int k = 0; k < 30; ++k) h2[k] = splat2(b2[k]);
#pragma unroll
  for (int i = 0; i < 30; ++i) {
    const f2 hi = h1[i];
#pragma unroll
    for (int k = 0; k < 30; ++k)
      h2[k] = __builtin_elementwise_fma(hi, splat2(W2[i * 30 + k]), h2[k]);
  }

  // output layer
  f2 y = zero;
#pragma unroll
  for (int k = 0; k < 30; ++k)
    y = __builtin_elementwise_fma(__builtin_elementwise_max(h2[k], zero),
                                  splat2(W3[k]), y);
  return y;
}

// R2's proven store loop: threads t<200, addr = base + t*16B + it*3200B.
// 3200 % 128 == 0 -> every wave-slice store covers whole 128B lines exactly
// (ideal WRITE_SIZE). cpr/pmx live in registers; 1 ds_read_b32 per iter.
__device__ __forceinline__ void store_batch(float* __restrict__ op0,
                                            const float* __restrict__ ytd,
                                            const float4 cpr, const float4 pmx,
                                            int t) {
  if (t < 200) {
    const int g = t % 25;
    int r = t / 25;
    float* __restrict__ op = op0 + r * 100 + g * 4;
#pragma unroll 4
    for (int it = 0; it < 64; ++it) {
      const float td = ytd[r];
      float4 v;
      v.x = fminf(fmaxf(td - cpr.x, 0.0f), pmx.x);
      v.y = fminf(fmaxf(td - cpr.y, 0.0f), pmx.y);
      v.z = fminf(fmaxf(td - cpr.z, 0.0f), pmx.z);
      v.w = fminf(fmaxf(td - cpr.w, 0.0f), pmx.w);
      *(float4*)op = v;
      r += 8;
      op += 800;
    }
  }
}

__global__ __launch_bounds__(256, 1) void e2e_mlp_fused_kernel(
    const float* __restrict__ x,    const float* __restrict__ Cost,
    const float* __restrict__ Pmax, const float* __restrict__ Pd,
    const float* __restrict__ wcapp,const float* __restrict__ W1,
    const float* __restrict__ b1,   const float* __restrict__ W2,
    const float* __restrict__ b2,   const float* __restrict__ W3,
    const float* __restrict__ b3p,  float* __restrict__ out) {
  __shared__ float s[SMEM_FLOATS];
  const int t = threadIdx.x;
  const int lane = t & 63;
  const long rbase = (long)blockIdx.x * 1024;

  // all x loads issued up front (latency hidden under cumprev / layer 1)
  const float4* __restrict__ x4 = (const float4*)x;
  const float4 xA0 = x4[rbase + t];
  const float4 xA1 = x4[rbase + 256 + t];
  const float4 xB0 = x4[rbase + 512 + t];
  const float4 xB1 = x4[rbase + 768 + t];

  // per-wave sum(Pd): lanes 0..24 float4 partials, shuffle reduce, broadcast
  float p = 0.0f;
  if (lane < 25) {
    const float4 q = ((const float4*)Pd)[lane];
    p = q.x + q.y + q.z + q.w;
  }
#pragma unroll
  for (int off = 32; off; off >>= 1) p += __shfl_down(p, off, 64);
  const float spd = __shfl(p, 0, 64);

  // cumprev (t<100): inner Cost[i]/Pmax[i] are uniform -> scalar loads,
  // contiguous -> batched. Stable tie-break == jnp stable argsort.
  if (t < 100) {
    const float c = Cost[t];
    float acc = 0.0f;
#pragma unroll 4
    for (int i = 0; i < 100; ++i) {
      const float ci = Cost[i];
      acc += ((ci < c) || (ci == c && i < t)) ? Pmax[i] : 0.0f;
    }
    s[OFF_CP + t] = acc;
  }

  const float wc = wcapp[0];
  const float Aconst = spd - wc * b3p[0];

  // ---- chain 0: rows [rbase, rbase+512) ----
  {
    const f2 y = mlp_pair(xA0, xA1, W1, b1, W2, b2, W3);
    s[OFF_TD + t]       = Aconst - wc * y.x;
    s[OFF_TD + 256 + t] = Aconst - wc * y.y;
  }
  __syncthreads();  // B1: cumprev + td[0..512) visible; no stores outstanding

  float4 cpr = {0, 0, 0, 0}, pmx = {0, 0, 0, 0};
  if (t < 200) {
    const int g = t % 25;
    cpr = *(const float4*)&s[OFF_CP + g * 4];
    pmx = ((const float4*)Pmax)[g];
  }

  // batch-0 stores issue; chain-1 compute overlaps their drain
  store_batch(out + rbase * 100, &s[OFF_TD], cpr, pmx, t);

  // ---- chain 1: rows [rbase+512, rbase+1024) ----
  {
    const f2 y = mlp_pair(xB0, xB1, W1, b1, W2, b2, W3);
    s[OFF_TD + 512 + t] = Aconst - wc * y.x;
    s[OFF_TD + 768 + t] = Aconst - wc * y.y;
  }
  __syncthreads();  // B2: td[512..1024) visible

  store_batch(out + (rbase + 512) * 100, &s[OFF_TD + 512], cpr, pmx, t);
}

extern "C" void kernel_launch(void* const* d_in, const int* in_sizes, int n_in,
                              void* d_out, int out_size, void* d_ws, size_t ws_size,
                              hipStream_t stream) {
  const float* x    = (const float*)d_in[0];
  const float* Cost = (const float*)d_in[1];
  const float* Pmax = (const float*)d_in[2];
  const float* Pd   = (const float*)d_in[3];
  const float* wcap = (const float*)d_in[4];
  const float* W1   = (const float*)d_in[5];
  const float* b1   = (const float*)d_in[6];
  const float* W2   = (const float*)d_in[7];
  const float* b2   = (const float*)d_in[8];
  const float* W3   = (const float*)d_in[9];
  const float* b3   = (const float*)d_in[10];
  float* out = (float*)d_out;

  e2e_mlp_fused_kernel<<<NBLOCKS, 256, 0, stream>>>(
      x, Cost, Pmax, Pd, wcap, W1, b1, W2, b2, W3, b3, out);
}

// Round 7
// 153.106 us; speedup vs baseline: 1.0270x; 1.0270x over previous
//
#include <hip/hip_runtime.h>
#include <hip/hip_bf16.h>

// R2 (best measured: ~21.5us kernel) with ONE change: the __syncthreads()
// barriers are replaced by "s_waitcnt lgkmcnt(0); s_barrier" (LDS-only wait).
// __syncthreads() emits s_waitcnt vmcnt(0) before s_barrier, which drains
// batch-0's ~8us of global stores before chain-1 compute can start -- pure
// serialization, since the barrier only protects the LDS td/cumprev exchange
// and the two store batches touch disjoint cache lines. With the LDS-only
// barrier, chain-1 compute overlaps the batch-0 drain:
//   stage(0.9) + chain0(2.7) + drain(16.1) ~= 19.7us vs 21.5.
// Staging loads are issued BEFORE x loads (vmcnt completes in order, so this
// keeps the staging ds_writes from waiting on the 16KB of x traffic).

typedef float f2 __attribute__((ext_vector_type(2)));

#define NBLOCKS 256

// LDS float offsets
#define OFF_W2 0      // [k*32+i]=W2[i][k] i<30; +30=b2[k]; +31=W3[k]  (960)
#define OFF_W1 960    // [k*8+i]=W1[i][k] i<4; +4=b1[k]; pads 0        (240)
#define OFF_CP 1200   // cumprev[100] (16B-aligned)
#define OFF_PM 1328   // Pmax[100]    (16B-aligned)
#define OFF_CS 1456   // Cost[100]
#define OFF_TD 1568   // tdbuf[1024 rows]
#define SMEM_FLOATS (OFF_TD + 1024)

// Barrier with LDS-only wait: does NOT drain outstanding global stores.
#define BARRIER_LDS() asm volatile("s_waitcnt lgkmcnt(0)\n\ts_barrier" ::: "memory")

__device__ __forceinline__ f2 splat2(float v) { return (f2){v, v}; }

// Packed MLP for two rows (xa -> .x lane, xb -> .y lane), weights from LDS.
__device__ __forceinline__ f2 mlp_pair(const float4 xa, const float4 xb,
                                       const float* __restrict__ s) {
  const f2 zero = {0.0f, 0.0f};
  const f2 X0 = {xa.x, xb.x}, X1 = {xa.y, xb.y};
  const f2 X2 = {xa.z, xb.z}, X3 = {xa.w, xb.w};

  f2 h1[30];
#pragma unroll
  for (int k = 0; k < 30; ++k) {
    const float4 wv = *(const float4*)&s[OFF_W1 + k * 8];
    const float bb = s[OFF_W1 + k * 8 + 4];
    f2 p = splat2(bb);
    p = __builtin_elementwise_fma(X0, splat2(wv.x), p);
    p = __builtin_elementwise_fma(X1, splat2(wv.y), p);
    p = __builtin_elementwise_fma(X2, splat2(wv.z), p);
    p = __builtin_elementwise_fma(X3, splat2(wv.w), p);
    h1[k] = __builtin_elementwise_max(p, zero);
  }

  f2 y = zero;
#pragma unroll 2
  for (int k = 0; k < 30; ++k) {
    const float4* __restrict__ wr = (const float4*)&s[OFF_W2 + k * 32];
    f2 sa = zero, sb = zero;
#pragma unroll
    for (int c = 0; c < 7; ++c) {
      const float4 wv = wr[c];
      sa = __builtin_elementwise_fma(h1[4 * c],     splat2(wv.x), sa);
      sb = __builtin_elementwise_fma(h1[4 * c + 1], splat2(wv.y), sb);
      sa = __builtin_elementwise_fma(h1[4 * c + 2], splat2(wv.z), sa);
      sb = __builtin_elementwise_fma(h1[4 * c + 3], splat2(wv.w), sb);
    }
    const float4 w7 = wr[7];  // {W2[28][k], W2[29][k], b2[k], W3[k]}
    sa = __builtin_elementwise_fma(h1[28], splat2(w7.x), sa);
    sb = __builtin_elementwise_fma(h1[29], splat2(w7.y), sb);
    f2 h2 = __builtin_elementwise_max(sa + sb + splat2(w7.z), zero);
    y = __builtin_elementwise_fma(h2, splat2(w7.w), y);
  }
  return y;
}

// Store loop (proven line-exact: addr = t*16B + it*3200B, 3200%128==0 and
// per-wave slices are 8/8/8/1 whole 128B lines -> ideal WRITE_SIZE).
__device__ __forceinline__ void store_batch(float* __restrict__ op0,
                                            const float* __restrict__ ytd,
                                            const float4 cpr, const float4 pmx,
                                            int t) {
  if (t < 200) {
    const int g = t % 25;
    int r = t / 25;
    float* __restrict__ op = op0 + r * 100 + g * 4;
#pragma unroll 4
    for (int it = 0; it < 64; ++it) {
      const float td = ytd[r];
      float4 v;
      v.x = fminf(fmaxf(td - cpr.x, 0.0f), pmx.x);
      v.y = fminf(fmaxf(td - cpr.y, 0.0f), pmx.y);
      v.z = fminf(fmaxf(td - cpr.z, 0.0f), pmx.z);
      v.w = fminf(fmaxf(td - cpr.w, 0.0f), pmx.w);
      *(float4*)op = v;
      r += 8;
      op += 800;
    }
  }
}

__global__ __launch_bounds__(256, 1) void e2e_mlp_fused_kernel(
    const float* __restrict__ x,    const float* __restrict__ Cost,
    const float* __restrict__ Pmax, const float* __restrict__ Pd,
    const float* __restrict__ wcapp,const float* __restrict__ W1,
    const float* __restrict__ b1,   const float* __restrict__ W2,
    const float* __restrict__ b2,   const float* __restrict__ W3,
    const float* __restrict__ b3p,  float* __restrict__ out) {
  __shared__ float s[SMEM_FLOATS];
  const int t = threadIdx.x;
  const int lane = t & 63;
  const long rbase = (long)blockIdx.x * 1024;

  // ---- stage weights FIRST (vmcnt completes in order: staging must not
  //      queue behind the 16KB of x loads) ----
  for (int idx = t; idx < 960; idx += 256) {
    const int k = idx >> 5, i = idx & 31;
    float v;
    if (i < 30)       v = W2[i * 30 + k];
    else if (i == 30) v = b2[k];
    else              v = W3[k];
    s[OFF_W2 + idx] = v;
  }
  if (t < 240) {
    const int k = t >> 3, i = t & 7;
    float v = 0.0f;
    if (i < 4)       v = W1[i * 30 + k];
    else if (i == 4) v = b1[k];
    s[OFF_W1 + t] = v;
  }
  if (t < 100) {
    s[OFF_CS + t] = Cost[t];
    s[OFF_PM + t] = Pmax[t];
  }

  // x loads issued after staging; consumed at MLP start (post-B0).
  const float4* __restrict__ x4 = (const float4*)x;
  const float4 xA0 = x4[rbase + t];
  const float4 xA1 = x4[rbase + 256 + t];
  const float4 xB0 = x4[rbase + 512 + t];
  const float4 xB1 = x4[rbase + 768 + t];

  // per-wave sum(Pd): lanes 0..24 float4 partials, shuffle reduce, broadcast
  float p = 0.0f;
  if (lane < 25) {
    const float4 q = ((const float4*)Pd)[lane];
    p = q.x + q.y + q.z + q.w;
  }
#pragma unroll
  for (int off = 32; off; off >>= 1) p += __shfl_down(p, off, 64);
  const float spd = __shfl(p, 0, 64);

  BARRIER_LDS();  // B0: staging visible

  // cumprev via O(N^2) rank-sum (stable tie-break == jnp stable argsort)
  if (t < 100) {
    const float c = s[OFF_CS + t];
    float acc = 0.0f;
    for (int i = 0; i < 100; ++i) {
      const float ci = s[OFF_CS + i];
      acc += ((ci < c) || (ci == c && i < t)) ? s[OFF_PM + i] : 0.0f;
    }
    s[OFF_CP + t] = acc;
  }

  const float wc = wcapp[0];
  const float Aconst = spd - wc * b3p[0];

  // ---- chain 0: rows [rbase, rbase+512) ----
  {
    const f2 y = mlp_pair(xA0, xA1, s);
    s[OFF_TD + t]       = Aconst - wc * y.x;
    s[OFF_TD + 256 + t] = Aconst - wc * y.y;
  }
  BARRIER_LDS();  // B1: cumprev + td[0..512) visible

  float4 cpr = {0, 0, 0, 0}, pmx = {0, 0, 0, 0};
  if (t < 200) {
    const int g = t % 25;
    cpr = *(const float4*)&s[OFF_CP + g * 4];
    pmx = *(const float4*)&s[OFF_PM + g * 4];
  }

  // batch-0 stores issue; chain-1 compute overlaps their drain (no vmcnt
  // drain at B2 -- the key change vs R2).
  store_batch(out + rbase * 100, &s[OFF_TD], cpr, pmx, t);

  // ---- chain 1: rows [rbase+512, rbase+1024) ----
  {
    const f2 y = mlp_pair(xB0, xB1, s);
    s[OFF_TD + 512 + t] = Aconst - wc * y.x;
    s[OFF_TD + 768 + t] = Aconst - wc * y.y;
  }
  BARRIER_LDS();  // B2: td[512..1024) visible; batch-0 stores still in flight

  store_batch(out + (rbase + 512) * 100, &s[OFF_TD + 512], cpr, pmx, t);
}

extern "C" void kernel_launch(void* const* d_in, const int* in_sizes, int n_in,
                              void* d_out, int out_size, void* d_ws, size_t ws_size,
                              hipStream_t stream) {
  const float* x    = (const float*)d_in[0];
  const float* Cost = (const float*)d_in[1];
  const float* Pmax = (const float*)d_in[2];
  const float* Pd   = (const float*)d_in[3];
  const float* wcap = (const float*)d_in[4];
  const float* W1   = (const float*)d_in[5];
  const float* b1   = (const float*)d_in[6];
  const float* W2   = (const float*)d_in[7];
  const float* b2   = (const float*)d_in[8];
  const float* W3   = (const float*)d_in[9];
  const float* b3   = (const float*)d_in[10];
  float* out = (float*)d_out;

  e2e_mlp_fused_kernel<<<NBLOCKS, 256, 0, stream>>>(
      x, Cost, Pmax, Pd, wcap, W1, b1, W2, b2, W3, b3, out);
}